// Round 6
// baseline (330.336 us; speedup 1.0000x reference)
//
#include <hip/hip_runtime.h>

// ---------------------------------------------------------------------------
// SpectralEncoder: ChebConv(K=4) x2 + mu/logvar heads.  bf16 features, MFMA
// GEMMs, wave-per-node gather props, folded Chebyshev weights.
// R5: unshard atomics (R4 null); fuse edges+concat+pack into one dispatch
//     (concat/pack traffic hides under atomic stalls); 4-edge ILP in the
//     atomic and scatter kernels; exact-guarded prop tail.
// ---------------------------------------------------------------------------

typedef __bf16 bf16x8 __attribute__((ext_vector_type(8)));
typedef float f32x4 __attribute__((ext_vector_type(4)));
typedef unsigned int uint32;
typedef unsigned short ushort16;

__device__ inline ushort16 f2bf(float f) {            // RNE fp32 -> bf16
    uint32 x = __float_as_uint(f);
    uint32 r = x + 0x7fffu + ((x >> 16) & 1u);
    return (ushort16)(r >> 16);
}
__device__ inline float bflo(uint32 v) { return __uint_as_float(v << 16); }
__device__ inline float bfhi(uint32 v) { return __uint_as_float(v & 0xffff0000u); }

// ---------------- weight transform (folded Chebyshev recurrence) -----------
// out = h(W0-W2) + Ph(W1-3W3) + P^2h(2W2) + P^3h(4W3)   (exact fp32 algebra)

__device__ inline float wtrans(const float* __restrict__ W, int kb, size_t o) {
    switch (kb) {
        case 0:  return W[o] - W[o + 32768];
        case 1:  return W[o + 16384] - 3.f * W[o + 49152];
        case 2:  return 2.f * W[o + 32768];
        default: return 4.f * W[o + 49152];
    }
}

// ---------------- fused prep: edge atomics + concat + weight pack ----------
// blocks [0,EB): 4 edges/thread, deg/cnt atomics + pos reservation
// blocks [EB,EB+CB): concat x|pe -> bf16 h (4 uint32 pairs/thread)
// blocks [EB+CB,..): pack W1/W2 (transformed) + head weights into B-frag order

__global__ void k_prep(const int* __restrict__ src, const int* __restrict__ dst,
                       const float* __restrict__ ew, float* __restrict__ deg,
                       int* __restrict__ cnt, int* __restrict__ pos, int E,
                       const float* __restrict__ x, const float* __restrict__ pe,
                       uint32* __restrict__ h, int N,
                       const float* __restrict__ W1, const float* __restrict__ W2,
                       const float* __restrict__ Wm, const float* __restrict__ Wl,
                       ushort16* __restrict__ W1p, ushort16* __restrict__ W2p,
                       ushort16* __restrict__ WHp, int EB, int CB) {
    const int b = blockIdx.x;
    const int tid = threadIdx.x;
    if (b < EB) {                       // ---- edge atomics, 4 edges/thread
        int e = (b * 256 + tid) * 4;
        if (e + 3 < E) {
            int4 s4 = *(const int4*)&src[e];
            int4 d4 = *(const int4*)&dst[e];
            float4 w4 = *(const float4*)&ew[e];
            atomicAdd(&deg[s4.x], w4.x);
            atomicAdd(&deg[s4.y], w4.y);
            atomicAdd(&deg[s4.z], w4.z);
            atomicAdd(&deg[s4.w], w4.w);
            int4 p4;
            p4.x = atomicAdd(&cnt[d4.x], 1);
            p4.y = atomicAdd(&cnt[d4.y], 1);
            p4.z = atomicAdd(&cnt[d4.z], 1);
            p4.w = atomicAdd(&cnt[d4.w], 1);
            *(int4*)&pos[e] = p4;
        } else {
            for (int q = 0; q < 4; ++q) {
                int ee = e + q;
                if (ee < E) {
                    atomicAdd(&deg[src[ee]], ew[ee]);
                    pos[ee] = atomicAdd(&cnt[dst[ee]], 1);
                }
            }
        }
    } else if (b < EB + CB) {           // ---- concat -> bf16 (8 feats/thread)
        int i4 = ((b - EB) * 256 + tid) * 4;    // 4 consecutive uint32 pairs
        if (i4 >= N * 64) return;
        int node = i4 >> 6, p = i4 & 63;        // chunk never crosses node/x-pe
        float4 fa, fb;
        if (p < 56) {
            const float* xp = &x[(size_t)node * 112 + p * 2];
            fa = *(const float4*)xp; fb = *(const float4*)(xp + 4);
        } else {
            const float* pp = &pe[(size_t)node * 16 + (p - 56) * 2];
            fa = *(const float4*)pp; fb = *(const float4*)(pp + 4);
        }
        int4 o;
        o.x = (uint32)f2bf(fa.x) | ((uint32)f2bf(fa.y) << 16);
        o.y = (uint32)f2bf(fa.z) | ((uint32)f2bf(fa.w) << 16);
        o.z = (uint32)f2bf(fb.x) | ((uint32)f2bf(fb.y) << 16);
        o.w = (uint32)f2bf(fb.z) | ((uint32)f2bf(fb.w) << 16);
        *(int4*)&h[i4] = o;
    } else {                            // ---- weight packing
        int t = (b - EB - CB) * 256 + tid;
        uint32 v[8];
        if (t < 16384) {                // layer packs: 2 x 16 ks x 8 c x 64 l
            const float* W = (t < 8192) ? W1 : W2;
            ushort16* Wp = (t < 8192) ? W1p : W2p;
            int tt = t & 8191;
            int l = tt & 63, c = (tt >> 6) & 7, ks = tt >> 9;
            int kb = ks >> 2;
            int r0 = (ks & 3) * 32 + (l >> 4) * 8;
            int col = c * 16 + (l & 15);
            #pragma unroll
            for (int j = 0; j < 8; ++j)
                v[j] = f2bf(wtrans(W, kb, (size_t)(r0 + j) * 128 + col));
            uint4 o;
            o.x = v[0] | (v[1] << 16); o.y = v[2] | (v[3] << 16);
            o.z = v[4] | (v[5] << 16); o.w = v[6] | (v[7] << 16);
            *(uint4*)(Wp + (size_t)tt * 8) = o;
        } else if (t < 16384 + 2048) {  // head pack: cols = [mu | lv]
            int tt = t - 16384;
            int l = tt & 63, c = (tt >> 6) & 7, ks = tt >> 9;
            int k0 = ks * 32 + (l >> 4) * 8;
            int cc = c * 16 + (l & 15);
            const float* Ws = (cc < 64) ? Wm : Wl;
            int col = cc & 63;
            #pragma unroll
            for (int j = 0; j < 8; ++j) v[j] = f2bf(Ws[(size_t)(k0 + j) * 64 + col]);
            uint4 o;
            o.x = v[0] | (v[1] << 16); o.y = v[2] | (v[3] << 16);
            o.z = v[4] | (v[5] << 16); o.w = v[6] | (v[7] << 16);
            *(uint4*)(WHp + (size_t)tt * 8) = o;
        }
    }
}

// --- scan phase A: 256 thr/block scan 1024 elems, local prefixes + total ---
__global__ void k_scan_blk(const int* __restrict__ cnt, int* __restrict__ row_ptr,
                           int* __restrict__ blk_sums, int N) {
    __shared__ int wsum[4];
    const int tid = threadIdx.x;
    const int base = blockIdx.x * 1024 + tid * 4;
    int4 v = make_int4(0, 0, 0, 0);
    if (base + 3 < N) v = *(const int4*)&cnt[base];
    else {
        if (base + 0 < N) v.x = cnt[base + 0];
        if (base + 1 < N) v.y = cnt[base + 1];
        if (base + 2 < N) v.z = cnt[base + 2];
    }
    const int tsum = v.x + v.y + v.z + v.w;
    const int lane = tid & 63;
    const int wv = tid >> 6;
    int incl = tsum;
    #pragma unroll
    for (int off = 1; off < 64; off <<= 1) {
        int t = __shfl_up(incl, off);
        if (lane >= off) incl += t;
    }
    if (lane == 63) wsum[wv] = incl;
    __syncthreads();
    int woff = 0;
    #pragma unroll
    for (int w = 0; w < 4; ++w) if (w < wv) woff += wsum[w];
    const int excl = woff + incl - tsum;
    if (base + 0 < N) row_ptr[base + 0] = excl;
    if (base + 1 < N) row_ptr[base + 1] = excl + v.x;
    if (base + 2 < N) row_ptr[base + 2] = excl + v.x + v.y;
    if (base + 3 < N) row_ptr[base + 3] = excl + v.x + v.y + v.z;
    if (tid == 255) blk_sums[blockIdx.x] = woff + incl;
}

// --- scan phase B: one wave scans block totals (nblk <= 64) ----------------
__global__ void k_scan_top(int* __restrict__ blk_sums, int* __restrict__ row_ptr,
                           int nblk, int N) {
    const int lane = threadIdx.x;
    int v = (lane < nblk) ? blk_sums[lane] : 0;
    int incl = v;
    #pragma unroll
    for (int off = 1; off < 64; off <<= 1) {
        int t = __shfl_up(incl, off);
        if (lane >= off) incl += t;
    }
    if (lane < nblk) blk_sums[lane] = incl - v;
    if (lane == 63) row_ptr[N] = incl;
}

// --- scan phase C fused with dis = rsqrt(deg) ------------------------------
__global__ void k_fix_dis(int* __restrict__ row_ptr, const int* __restrict__ blk_sums,
                          const float* __restrict__ deg, float* __restrict__ dis, int N) {
    int i = blockIdx.x * blockDim.x + threadIdx.x;
    if (i >= N) return;
    row_ptr[i] += blk_sums[i >> 10];
    float d = deg[i];
    dis[i] = d > 0.f ? rsqrtf(fmaxf(d, 1e-12f)) : 0.f;
}

// --- atomic-free scatter, 4 edges/thread: csr[row_ptr[d]+pos] = {src,w} ----
__global__ void k_scatter(const int* __restrict__ src, const int* __restrict__ dst,
                          const float* __restrict__ ew, const float* __restrict__ dis,
                          const int* __restrict__ row_ptr, const int* __restrict__ pos,
                          int2* __restrict__ csr, int E) {
    int e = (blockIdx.x * blockDim.x + threadIdx.x) * 4;
    if (e + 3 < E) {
        int4 s4 = *(const int4*)&src[e];
        int4 d4 = *(const int4*)&dst[e];
        float4 w4 = *(const float4*)&ew[e];
        int4 p4 = *(const int4*)&pos[e];
        csr[row_ptr[d4.x] + p4.x] = make_int2(s4.x, __float_as_int(-dis[s4.x] * w4.x * dis[d4.x]));
        csr[row_ptr[d4.y] + p4.y] = make_int2(s4.y, __float_as_int(-dis[s4.y] * w4.y * dis[d4.y]));
        csr[row_ptr[d4.z] + p4.z] = make_int2(s4.z, __float_as_int(-dis[s4.z] * w4.z * dis[d4.z]));
        csr[row_ptr[d4.w] + p4.w] = make_int2(s4.w, __float_as_int(-dis[s4.w] * w4.w * dis[d4.w]));
    } else {
        for (int q = 0; q < 4; ++q) {
            int ee = e + q;
            if (ee < E) {
                int s = src[ee], d = dst[ee];
                float wv = -dis[s] * ew[ee] * dis[d];
                csr[row_ptr[d] + pos[ee]] = make_int2(s, __float_as_int(wv));
            }
        }
    }
}

// ---------------- pure gather prop: out = P * tin  (bf16 features) ---------
// wave per node; lane covers 2 feats; full rounds of 8 unguarded + exact tail.

__global__ void k_prop(const uint32* __restrict__ tin, const int2* __restrict__ csr,
                       const int* __restrict__ row_ptr, uint32* __restrict__ out, int N) {
    int wid = (blockIdx.x * blockDim.x + threadIdx.x) >> 6;
    int lane = threadIdx.x & 63;
    if (wid >= N) return;
    int beg = row_ptr[wid], end = row_ptr[wid + 1];
    float ax = 0.f, ay = 0.f;
    for (int base = beg; base < end; base += 64) {
        int m = end - base; if (m > 64) m = 64;
        int2 ev = (lane < m) ? csr[base + lane] : make_int2(0, 0);
        int full = m & ~7;
        for (int j = 0; j < full; j += 8) {
            #pragma unroll
            for (int u = 0; u < 8; ++u) {
                int s = __shfl(ev.x, j + u);
                float w = __uint_as_float(__shfl(ev.y, j + u));
                uint32 v = tin[(size_t)s * 64 + lane];
                ax = fmaf(w, bflo(v), ax); ay = fmaf(w, bfhi(v), ay);
            }
        }
        #pragma unroll
        for (int u = 0; u < 8; ++u) {          // wave-uniform guards
            if (full + u < m) {
                int s = __shfl(ev.x, full + u);
                float w = __uint_as_float(__shfl(ev.y, full + u));
                uint32 v = tin[(size_t)s * 64 + lane];
                ax = fmaf(w, bflo(v), ax); ay = fmaf(w, bfhi(v), ay);
            }
        }
    }
    out[(size_t)wid * 64 + lane] = (uint32)f2bf(ax) | ((uint32)f2bf(ay) << 16);
}

// ---------------- MFMA GEMM: C[N,128] = relu(sum_t T_t @ W_t + b), K=512 ---

template<bool RELU>
__launch_bounds__(256)
__global__ void k_mfma_gemm512(const ushort16* __restrict__ t0, const ushort16* __restrict__ t1,
                               const ushort16* __restrict__ t2, const ushort16* __restrict__ t3,
                               const ushort16* __restrict__ Wp, const float* __restrict__ bias,
                               ushort16* __restrict__ C, int N) {
    const int lane = threadIdx.x & 63;
    const int wave = threadIdx.x >> 6;
    const int brow = blockIdx.x * 128 + wave * 32;
    int r0 = brow + (lane & 15);
    int r1 = r0 + 16;
    if (r0 >= N) r0 = N - 1;
    if (r1 >= N) r1 = N - 1;
    const int kg8 = (lane >> 4) * 8;
    f32x4 acc[2][8] = {};
    #pragma unroll
    for (int t = 0; t < 4; ++t) {
        const ushort16* __restrict__ A = (t == 0) ? t0 : (t == 1) ? t1 : (t == 2) ? t2 : t3;
        const ushort16* a0p = A + (size_t)r0 * 128 + kg8;
        const ushort16* a1p = A + (size_t)r1 * 128 + kg8;
        #pragma unroll
        for (int ks2 = 0; ks2 < 4; ++ks2) {
            bf16x8 a0 = *(const bf16x8*)(a0p + ks2 * 32);
            bf16x8 a1 = *(const bf16x8*)(a1p + ks2 * 32);
            const ushort16* bp = Wp + (size_t)((t * 4 + ks2) * 8 * 64 + lane) * 8;
            #pragma unroll
            for (int c = 0; c < 8; ++c) {
                bf16x8 b = *(const bf16x8*)(bp + c * 512);
                acc[0][c] = __builtin_amdgcn_mfma_f32_16x16x32_bf16(a0, b, acc[0][c], 0, 0, 0);
                acc[1][c] = __builtin_amdgcn_mfma_f32_16x16x32_bf16(a1, b, acc[1][c], 0, 0, 0);
            }
        }
    }
    const int col0 = lane & 15;
    const int rj = (lane >> 4) * 4;
    #pragma unroll
    for (int m = 0; m < 2; ++m) {
        #pragma unroll
        for (int c = 0; c < 8; ++c) {
            float bv = bias[c * 16 + col0];
            #pragma unroll
            for (int j = 0; j < 4; ++j) {
                int row = brow + m * 16 + rj + j;
                if (row < N) {
                    float v = acc[m][c][j] + bv;
                    if (RELU) v = fmaxf(v, 0.f);
                    C[(size_t)row * 128 + c * 16 + col0] = f2bf(v);
                }
            }
        }
    }
}

// ---------------- fused heads via MFMA: [N,128]@[128,128], cols=[mu|lv] ----

__launch_bounds__(256)
__global__ void k_mfma_head(const ushort16* __restrict__ A, const ushort16* __restrict__ Wp,
                            const float* __restrict__ bm, const float* __restrict__ bl,
                            float* __restrict__ out, int N) {
    const int lane = threadIdx.x & 63;
    const int wave = threadIdx.x >> 6;
    const int brow = blockIdx.x * 128 + wave * 32;
    int r0 = brow + (lane & 15);
    int r1 = r0 + 16;
    if (r0 >= N) r0 = N - 1;
    if (r1 >= N) r1 = N - 1;
    const int kg8 = (lane >> 4) * 8;
    f32x4 acc[2][8] = {};
    const ushort16* a0p = A + (size_t)r0 * 128 + kg8;
    const ushort16* a1p = A + (size_t)r1 * 128 + kg8;
    #pragma unroll
    for (int ks = 0; ks < 4; ++ks) {
        bf16x8 a0 = *(const bf16x8*)(a0p + ks * 32);
        bf16x8 a1 = *(const bf16x8*)(a1p + ks * 32);
        const ushort16* bp = Wp + (size_t)(ks * 8 * 64 + lane) * 8;
        #pragma unroll
        for (int c = 0; c < 8; ++c) {
            bf16x8 b = *(const bf16x8*)(bp + c * 512);
            acc[0][c] = __builtin_amdgcn_mfma_f32_16x16x32_bf16(a0, b, acc[0][c], 0, 0, 0);
            acc[1][c] = __builtin_amdgcn_mfma_f32_16x16x32_bf16(a1, b, acc[1][c], 0, 0, 0);
        }
    }
    const int col0 = lane & 15;
    const int rj = (lane >> 4) * 4;
    #pragma unroll
    for (int m = 0; m < 2; ++m) {
        #pragma unroll
        for (int c = 0; c < 8; ++c) {
            int gcol = (c & 3) * 16 + col0;
            float bv = (c < 4) ? bm[gcol] : bl[gcol];
            size_t hoff = (c < 4) ? 0 : (size_t)N * 64;
            #pragma unroll
            for (int j = 0; j < 4; ++j) {
                int row = brow + m * 16 + rj + j;
                if (row < N)
                    out[hoff + (size_t)row * 64 + gcol] = acc[m][c][j] + bv;
            }
        }
    }
}

// ---------------------------------------------------------------------------

extern "C" void kernel_launch(void* const* d_in, const int* in_sizes, int n_in,
                              void* d_out, int out_size, void* d_ws, size_t ws_size,
                              hipStream_t stream) {
    const float* x   = (const float*)d_in[0];
    const int*   ei  = (const int*)d_in[1];
    const float* pe  = (const float*)d_in[2];
    const float* ew  = (const float*)d_in[3];
    const float* W1  = (const float*)d_in[4];
    const float* b1  = (const float*)d_in[5];
    const float* W2  = (const float*)d_in[6];
    const float* b2  = (const float*)d_in[7];
    const float* Wmu = (const float*)d_in[8];
    const float* bmu = (const float*)d_in[9];
    const float* Wlv = (const float*)d_in[10];
    const float* blv = (const float*)d_in[11];

    const int N = in_sizes[0] / 112;
    const int E = in_sizes[1] / 2;
    const int* src = ei;
    const int* dst = ei + E;

    char* ws = (char*)d_ws;
    size_t off = 0;
    auto alloc = [&](size_t bytes) -> char* {
        char* p = ws + off;
        off = (off + bytes + 255) & ~(size_t)255;
        return p;
    };
    float* deg     = (float*)alloc((size_t)N * 4);
    int*   cnt     = (int*)  alloc((size_t)N * 4);
    float* dis     = (float*)alloc((size_t)N * 4);
    int*   row_ptr = (int*)  alloc((size_t)(N + 1) * 4);
    int*   blk_sums= (int*)  alloc((size_t)256 * 4);
    int*   pos     = (int*)  alloc((size_t)E * 4);
    int2*  csr     = (int2*) alloc((size_t)E * 8);
    ushort16* W1p  = (ushort16*)alloc((size_t)512 * 128 * 2);
    ushort16* W2p  = (ushort16*)alloc((size_t)512 * 128 * 2);
    ushort16* WHp  = (ushort16*)alloc((size_t)128 * 128 * 2);
    ushort16* B0 = (ushort16*)alloc((size_t)N * 128 * 2);
    ushort16* B1 = (ushort16*)alloc((size_t)N * 128 * 2);
    ushort16* B2 = (ushort16*)alloc((size_t)N * 128 * 2);
    ushort16* B3 = (ushort16*)alloc((size_t)N * 128 * 2);
    ushort16* B4 = (ushort16*)alloc((size_t)N * 128 * 2);

    hipMemsetAsync(deg, 0, (size_t)N * 4, stream);
    hipMemsetAsync(cnt, 0, (size_t)N * 4, stream);

    const int nb = (N + 255) / 256;
    const int pb = (N + 3) / 4;          // wave-per-node, 4 waves/block
    const int gb = (N + 127) / 128;      // 128 rows/block MFMA tiles
    const int nblk = (N + 1023) / 1024;  // 49 for N=50000 (<= 64 required)
    const int EB = (E + 1023) / 1024;                 // edge blocks (4/thread)
    const int CB = (N * 64 + 1023) / 1024;            // concat blocks (4 pairs/thr)
    const int PB = (16384 + 2048 + 255) / 256;        // pack blocks

    k_prep<<<EB + CB + PB, 256, 0, stream>>>(src, dst, ew, deg, cnt, pos, E,
                                             x, pe, (uint32*)B0, N,
                                             W1, W2, Wmu, Wlv, W1p, W2p, WHp, EB, CB);
    k_scan_blk<<<nblk, 256, 0, stream>>>(cnt, row_ptr, blk_sums, N);
    k_scan_top<<<1, 64, 0, stream>>>(blk_sums, row_ptr, nblk, N);
    k_fix_dis<<<nb, 256, 0, stream>>>(row_ptr, blk_sums, deg, dis, N);
    k_scatter<<<(E + 1023) / 1024, 256, 0, stream>>>(src, dst, ew, dis, row_ptr, pos, csr, E);

    // layer 1: Y1=P*B0, Y2=P*Y1, Y3=P*Y2 -> gemm(transformed W1) -> relu -> B4
    k_prop<<<pb, 256, 0, stream>>>((uint32*)B0, csr, row_ptr, (uint32*)B1, N);
    k_prop<<<pb, 256, 0, stream>>>((uint32*)B1, csr, row_ptr, (uint32*)B2, N);
    k_prop<<<pb, 256, 0, stream>>>((uint32*)B2, csr, row_ptr, (uint32*)B3, N);
    k_mfma_gemm512<true><<<gb, 256, 0, stream>>>(B0, B1, B2, B3, W1p, b1, B4, N);

    // layer 2: Y1=P*B4, Y2, Y3 -> gemm(transformed W2) -> relu -> B3
    k_prop<<<pb, 256, 0, stream>>>((uint32*)B4, csr, row_ptr, (uint32*)B0, N);
    k_prop<<<pb, 256, 0, stream>>>((uint32*)B0, csr, row_ptr, (uint32*)B1, N);
    k_prop<<<pb, 256, 0, stream>>>((uint32*)B1, csr, row_ptr, (uint32*)B2, N);
    k_mfma_gemm512<true><<<gb, 256, 0, stream>>>(B4, B0, B1, B2, W2p, b2, B3, N);

    // heads -> d_out = [mu ; logvar] fp32
    k_mfma_head<<<gb, 256, 0, stream>>>(B3, WHp, bmu, blv, (float*)d_out, N);
}

// Round 7
// 314.384 us; speedup vs baseline: 1.0507x; 1.0507x over previous
//
#include <hip/hip_runtime.h>

// ---------------------------------------------------------------------------
// SpectralEncoder: ChebConv(K=4) x2 + mu/logvar heads.  bf16 features, MFMA
// GEMMs, wave-per-node gather props, folded Chebyshev weights.
// R6: revert R5 fusion (regressed). XCD-partitioned counters with
//     workgroup-scope (L2-local, no sc1) atomics: deg8/cnt8[xcc][node],
//     pos=(rank<<3)|xcc, per-shard bases in fix_dis. Device-scope atomics
//     measured ~17G/s flat (R3/R4/R5) -> shared cross-XCD unit; L2-local
//     atomics run on 8 independent L2s.
// ---------------------------------------------------------------------------

typedef __bf16 bf16x8 __attribute__((ext_vector_type(8)));
typedef float f32x4 __attribute__((ext_vector_type(4)));
typedef unsigned int uint32;
typedef unsigned short ushort16;

__device__ inline ushort16 f2bf(float f) {            // RNE fp32 -> bf16
    uint32 x = __float_as_uint(f);
    uint32 r = x + 0x7fffu + ((x >> 16) & 1u);
    return (ushort16)(r >> 16);
}
__device__ inline float bflo(uint32 v) { return __uint_as_float(v << 16); }
__device__ inline float bfhi(uint32 v) { return __uint_as_float(v & 0xffff0000u); }

__device__ inline int xcc_id() {                      // physical XCD id, 0..7
    int x;
    asm volatile("s_getreg_b32 %0, hwreg(HW_REG_XCC_ID)" : "=s"(x));
    return x & 7;
}

#define NXCD 8

// ---------------- graph preprocessing --------------------------------------
// XCD-local atomics: every updater of shard k runs on XCD k, so a
// workgroup-scope atomic (global_atomic without sc1, resolved in the local
// XCD L2) is atomic for all of them.

__global__ void k_deg_cnt(const int* __restrict__ src, const int* __restrict__ dst,
                          const float* __restrict__ ew, float* __restrict__ deg8,
                          int* __restrict__ cnt8, int* __restrict__ pos, int E, int N) {
    int e = blockIdx.x * blockDim.x + threadIdx.x;
    if (e >= E) return;
    int xcc = xcc_id();
    __hip_atomic_fetch_add(&deg8[xcc * N + src[e]], ew[e],
                           __ATOMIC_RELAXED, __HIP_MEMORY_SCOPE_WORKGROUP);
    int r = __hip_atomic_fetch_add(&cnt8[xcc * N + dst[e]], 1,
                                   __ATOMIC_RELAXED, __HIP_MEMORY_SCOPE_WORKGROUP);
    pos[e] = (r << 3) | xcc;
}

// --- scan phase A: per-node totals over 8 shards, block-local prefix -------
__global__ void k_scan_blk(const int* __restrict__ cnt8, int* __restrict__ row_ptr,
                           int* __restrict__ blk_sums, int N) {
    __shared__ int wsum[4];
    const int tid = threadIdx.x;
    const int base = blockIdx.x * 1024 + tid * 4;
    int4 v = make_int4(0, 0, 0, 0);
    #pragma unroll
    for (int s = 0; s < NXCD; ++s) {
        const int* c = cnt8 + (size_t)s * N;
        if (base + 3 < N) {
            int4 u = *(const int4*)&c[base];
            v.x += u.x; v.y += u.y; v.z += u.z; v.w += u.w;
        } else {
            if (base + 0 < N) v.x += c[base + 0];
            if (base + 1 < N) v.y += c[base + 1];
            if (base + 2 < N) v.z += c[base + 2];
        }
    }
    const int tsum = v.x + v.y + v.z + v.w;
    const int lane = tid & 63;
    const int wv = tid >> 6;
    int incl = tsum;
    #pragma unroll
    for (int off = 1; off < 64; off <<= 1) {
        int t = __shfl_up(incl, off);
        if (lane >= off) incl += t;
    }
    if (lane == 63) wsum[wv] = incl;
    __syncthreads();
    int woff = 0;
    #pragma unroll
    for (int w = 0; w < 4; ++w) if (w < wv) woff += wsum[w];
    const int excl = woff + incl - tsum;
    if (base + 0 < N) row_ptr[base + 0] = excl;
    if (base + 1 < N) row_ptr[base + 1] = excl + v.x;
    if (base + 2 < N) row_ptr[base + 2] = excl + v.x + v.y;
    if (base + 3 < N) row_ptr[base + 3] = excl + v.x + v.y + v.z;
    if (tid == 255) blk_sums[blockIdx.x] = woff + incl;
}

// --- scan phase B: one wave scans block totals (nblk <= 64) ----------------
__global__ void k_scan_top(int* __restrict__ blk_sums, int* __restrict__ row_ptr,
                           int nblk, int N) {
    const int lane = threadIdx.x;
    int v = (lane < nblk) ? blk_sums[lane] : 0;
    int incl = v;
    #pragma unroll
    for (int off = 1; off < 64; off <<= 1) {
        int t = __shfl_up(incl, off);
        if (lane >= off) incl += t;
    }
    if (lane < nblk) blk_sums[lane] = incl - v;
    if (lane == 63) row_ptr[N] = incl;
}

// --- scan phase C: global row_ptr, per-node shard bases, dis ---------------
__global__ void k_fix_dis(int* __restrict__ row_ptr, const int* __restrict__ blk_sums,
                          const int* __restrict__ cnt8, int* __restrict__ base8,
                          const float* __restrict__ deg8, float* __restrict__ dis, int N) {
    int i = blockIdx.x * blockDim.x + threadIdx.x;
    if (i >= N) return;
    int rp = row_ptr[i] + blk_sums[i >> 10];
    row_ptr[i] = rp;
    float d = 0.f;
    int acc = rp;
    #pragma unroll
    for (int s = 0; s < NXCD; ++s) {
        base8[(size_t)s * N + i] = acc;
        acc += cnt8[(size_t)s * N + i];
        d += deg8[(size_t)s * N + i];
    }
    dis[i] = d > 0.f ? rsqrtf(fmaxf(d, 1e-12f)) : 0.f;
}

// --- atomic-free scatter: csr[base8[xcc][dst]+rank] = {src, w_bits} --------
__global__ void k_scatter(const int* __restrict__ src, const int* __restrict__ dst,
                          const float* __restrict__ ew, const float* __restrict__ dis,
                          const int* __restrict__ base8, const int* __restrict__ pos,
                          int2* __restrict__ csr, int E, int N) {
    int e = blockIdx.x * blockDim.x + threadIdx.x;
    if (e >= E) return;
    int s = src[e], d = dst[e];
    float wv = -dis[s] * ew[e] * dis[d];
    int p = pos[e];
    int xcc = p & 7, rank = p >> 3;
    csr[base8[(size_t)xcc * N + d] + rank] = make_int2(s, __float_as_int(wv));
}

// ---------------- feature concat -> bf16 (8 feats/thread) ------------------

__global__ void k_concat_bf16(const float* __restrict__ x, const float* __restrict__ pe,
                              uint32* __restrict__ h, int N) {
    int i4 = (blockIdx.x * blockDim.x + threadIdx.x) * 4;  // 4 uint32 pairs
    if (i4 >= N * 64) return;
    int node = i4 >> 6, p = i4 & 63;      // chunk never crosses node/x-pe bound
    float4 fa, fb;
    if (p < 56) {
        const float* xp = &x[(size_t)node * 112 + p * 2];
        fa = *(const float4*)xp; fb = *(const float4*)(xp + 4);
    } else {
        const float* pp = &pe[(size_t)node * 16 + (p - 56) * 2];
        fa = *(const float4*)pp; fb = *(const float4*)(pp + 4);
    }
    int4 o;
    o.x = (uint32)f2bf(fa.x) | ((uint32)f2bf(fa.y) << 16);
    o.y = (uint32)f2bf(fa.z) | ((uint32)f2bf(fa.w) << 16);
    o.z = (uint32)f2bf(fb.x) | ((uint32)f2bf(fb.y) << 16);
    o.w = (uint32)f2bf(fb.z) | ((uint32)f2bf(fb.w) << 16);
    *(int4*)&h[i4] = o;
}

// ---------------- weight packing (fused, recurrence-transformed) -----------
// Layer transform (exact fp32): out = h(W0-W2) + Ph(W1-3W3) + P^2h(2W2) + P^3h(4W3)
// B-frag (16x16x32): lane l holds B[k=(l>>4)*8+j][col], j=0..7.

__device__ inline float wtrans(const float* __restrict__ W, int kb, size_t o) {
    switch (kb) {
        case 0:  return W[o] - W[o + 32768];
        case 1:  return W[o + 16384] - 3.f * W[o + 49152];
        case 2:  return 2.f * W[o + 32768];
        default: return 4.f * W[o + 49152];
    }
}

__global__ void k_pack_all(const float* __restrict__ W1, const float* __restrict__ W2,
                           const float* __restrict__ Wm, const float* __restrict__ Wl,
                           ushort16* __restrict__ W1p, ushort16* __restrict__ W2p,
                           ushort16* __restrict__ WHp) {
    int t = blockIdx.x * blockDim.x + threadIdx.x;
    uint32 v[8];
    if (t < 16384) {   // layer packs: 2 x 16 ks x 8 c x 64 lanes
        const float* W = (t < 8192) ? W1 : W2;
        ushort16* Wp = (t < 8192) ? W1p : W2p;
        int tt = t & 8191;
        int l = tt & 63, c = (tt >> 6) & 7, ks = tt >> 9;
        int kb = ks >> 2;
        int r0 = (ks & 3) * 32 + (l >> 4) * 8;
        int col = c * 16 + (l & 15);
        #pragma unroll
        for (int j = 0; j < 8; ++j)
            v[j] = f2bf(wtrans(W, kb, (size_t)(r0 + j) * 128 + col));
        uint4 o;
        o.x = v[0] | (v[1] << 16); o.y = v[2] | (v[3] << 16);
        o.z = v[4] | (v[5] << 16); o.w = v[6] | (v[7] << 16);
        *(uint4*)(Wp + (size_t)tt * 8) = o;
    } else if (t < 16384 + 2048) {   // head pack: cols = [mu | lv]
        int tt = t - 16384;
        int l = tt & 63, c = (tt >> 6) & 7, ks = tt >> 9;
        int k0 = ks * 32 + (l >> 4) * 8;
        int cc = c * 16 + (l & 15);
        const float* Ws = (cc < 64) ? Wm : Wl;
        int col = cc & 63;
        #pragma unroll
        for (int j = 0; j < 8; ++j) v[j] = f2bf(Ws[(size_t)(k0 + j) * 64 + col]);
        uint4 o;
        o.x = v[0] | (v[1] << 16); o.y = v[2] | (v[3] << 16);
        o.z = v[4] | (v[5] << 16); o.w = v[6] | (v[7] << 16);
        *(uint4*)(WHp + (size_t)tt * 8) = o;
    }
}

// ---------------- pure gather prop: out = P * tin  (bf16 features) ---------
// wave per node; lane covers 2 feats; 8 gathers in flight, zero-padded tail.

__global__ void k_prop(const uint32* __restrict__ tin, const int2* __restrict__ csr,
                       const int* __restrict__ row_ptr, uint32* __restrict__ out, int N) {
    int wid = (blockIdx.x * blockDim.x + threadIdx.x) >> 6;
    int lane = threadIdx.x & 63;
    if (wid >= N) return;
    int beg = row_ptr[wid], end = row_ptr[wid + 1];
    float ax = 0.f, ay = 0.f;
    for (int base = beg; base < end; base += 64) {
        int m = end - base; if (m > 64) m = 64;
        int2 ev = (lane < m) ? csr[base + lane] : make_int2(0, 0);
        for (int j = 0; j < m; j += 8) {
            #pragma unroll
            for (int u = 0; u < 8; ++u) {       // pad lanes have w=0
                int s = __shfl(ev.x, j + u);
                float w = __uint_as_float(__shfl(ev.y, j + u));
                uint32 v = tin[(size_t)s * 64 + lane];
                ax = fmaf(w, bflo(v), ax); ay = fmaf(w, bfhi(v), ay);
            }
        }
    }
    out[(size_t)wid * 64 + lane] = (uint32)f2bf(ax) | ((uint32)f2bf(ay) << 16);
}

// ---------------- MFMA GEMM: C[N,128] = relu(sum_t T_t @ W_t + b), K=512 ---

template<bool RELU>
__launch_bounds__(256)
__global__ void k_mfma_gemm512(const ushort16* __restrict__ t0, const ushort16* __restrict__ t1,
                               const ushort16* __restrict__ t2, const ushort16* __restrict__ t3,
                               const ushort16* __restrict__ Wp, const float* __restrict__ bias,
                               ushort16* __restrict__ C, int N) {
    const int lane = threadIdx.x & 63;
    const int wave = threadIdx.x >> 6;
    const int brow = blockIdx.x * 128 + wave * 32;
    int r0 = brow + (lane & 15);
    int r1 = r0 + 16;
    if (r0 >= N) r0 = N - 1;
    if (r1 >= N) r1 = N - 1;
    const int kg8 = (lane >> 4) * 8;
    f32x4 acc[2][8] = {};
    #pragma unroll
    for (int t = 0; t < 4; ++t) {
        const ushort16* __restrict__ A = (t == 0) ? t0 : (t == 1) ? t1 : (t == 2) ? t2 : t3;
        const ushort16* a0p = A + (size_t)r0 * 128 + kg8;
        const ushort16* a1p = A + (size_t)r1 * 128 + kg8;
        #pragma unroll
        for (int ks2 = 0; ks2 < 4; ++ks2) {
            bf16x8 a0 = *(const bf16x8*)(a0p + ks2 * 32);
            bf16x8 a1 = *(const bf16x8*)(a1p + ks2 * 32);
            const ushort16* bp = Wp + (size_t)((t * 4 + ks2) * 8 * 64 + lane) * 8;
            #pragma unroll
            for (int c = 0; c < 8; ++c) {
                bf16x8 b = *(const bf16x8*)(bp + c * 512);
                acc[0][c] = __builtin_amdgcn_mfma_f32_16x16x32_bf16(a0, b, acc[0][c], 0, 0, 0);
                acc[1][c] = __builtin_amdgcn_mfma_f32_16x16x32_bf16(a1, b, acc[1][c], 0, 0, 0);
            }
        }
    }
    const int col0 = lane & 15;
    const int rj = (lane >> 4) * 4;
    #pragma unroll
    for (int m = 0; m < 2; ++m) {
        #pragma unroll
        for (int c = 0; c < 8; ++c) {
            float bv = bias[c * 16 + col0];
            #pragma unroll
            for (int j = 0; j < 4; ++j) {
                int row = brow + m * 16 + rj + j;
                if (row < N) {
                    float v = acc[m][c][j] + bv;
                    if (RELU) v = fmaxf(v, 0.f);
                    C[(size_t)row * 128 + c * 16 + col0] = f2bf(v);
                }
            }
        }
    }
}

// ---------------- fused heads via MFMA: [N,128]@[128,128], cols=[mu|lv] ----

__launch_bounds__(256)
__global__ void k_mfma_head(const ushort16* __restrict__ A, const ushort16* __restrict__ Wp,
                            const float* __restrict__ bm, const float* __restrict__ bl,
                            float* __restrict__ out, int N) {
    const int lane = threadIdx.x & 63;
    const int wave = threadIdx.x >> 6;
    const int brow = blockIdx.x * 128 + wave * 32;
    int r0 = brow + (lane & 15);
    int r1 = r0 + 16;
    if (r0 >= N) r0 = N - 1;
    if (r1 >= N) r1 = N - 1;
    const int kg8 = (lane >> 4) * 8;
    f32x4 acc[2][8] = {};
    const ushort16* a0p = A + (size_t)r0 * 128 + kg8;
    const ushort16* a1p = A + (size_t)r1 * 128 + kg8;
    #pragma unroll
    for (int ks = 0; ks < 4; ++ks) {
        bf16x8 a0 = *(const bf16x8*)(a0p + ks * 32);
        bf16x8 a1 = *(const bf16x8*)(a1p + ks * 32);
        const ushort16* bp = Wp + (size_t)(ks * 8 * 64 + lane) * 8;
        #pragma unroll
        for (int c = 0; c < 8; ++c) {
            bf16x8 b = *(const bf16x8*)(bp + c * 512);
            acc[0][c] = __builtin_amdgcn_mfma_f32_16x16x32_bf16(a0, b, acc[0][c], 0, 0, 0);
            acc[1][c] = __builtin_amdgcn_mfma_f32_16x16x32_bf16(a1, b, acc[1][c], 0, 0, 0);
        }
    }
    const int col0 = lane & 15;
    const int rj = (lane >> 4) * 4;
    #pragma unroll
    for (int m = 0; m < 2; ++m) {
        #pragma unroll
        for (int c = 0; c < 8; ++c) {
            int gcol = (c & 3) * 16 + col0;
            float bv = (c < 4) ? bm[gcol] : bl[gcol];
            size_t hoff = (c < 4) ? 0 : (size_t)N * 64;
            #pragma unroll
            for (int j = 0; j < 4; ++j) {
                int row = brow + m * 16 + rj + j;
                if (row < N)
                    out[hoff + (size_t)row * 64 + gcol] = acc[m][c][j] + bv;
            }
        }
    }
}

// ---------------------------------------------------------------------------

extern "C" void kernel_launch(void* const* d_in, const int* in_sizes, int n_in,
                              void* d_out, int out_size, void* d_ws, size_t ws_size,
                              hipStream_t stream) {
    const float* x   = (const float*)d_in[0];
    const int*   ei  = (const int*)d_in[1];
    const float* pe  = (const float*)d_in[2];
    const float* ew  = (const float*)d_in[3];
    const float* W1  = (const float*)d_in[4];
    const float* b1  = (const float*)d_in[5];
    const float* W2  = (const float*)d_in[6];
    const float* b2  = (const float*)d_in[7];
    const float* Wmu = (const float*)d_in[8];
    const float* bmu = (const float*)d_in[9];
    const float* Wlv = (const float*)d_in[10];
    const float* blv = (const float*)d_in[11];

    const int N = in_sizes[0] / 112;
    const int E = in_sizes[1] / 2;
    const int* src = ei;
    const int* dst = ei + E;

    char* ws = (char*)d_ws;
    size_t off = 0;
    auto alloc = [&](size_t bytes) -> char* {
        char* p = ws + off;
        off = (off + bytes + 255) & ~(size_t)255;
        return p;
    };
    float* deg8    = (float*)alloc((size_t)N * 4 * NXCD);
    int*   cnt8    = (int*)  alloc((size_t)N * 4 * NXCD);
    int*   base8   = (int*)  alloc((size_t)N * 4 * NXCD);
    float* dis     = (float*)alloc((size_t)N * 4);
    int*   row_ptr = (int*)  alloc((size_t)(N + 1) * 4);
    int*   blk_sums= (int*)  alloc((size_t)256 * 4);
    int*   pos     = (int*)  alloc((size_t)E * 4);
    int2*  csr     = (int2*) alloc((size_t)E * 8);
    ushort16* W1p  = (ushort16*)alloc((size_t)512 * 128 * 2);
    ushort16* W2p  = (ushort16*)alloc((size_t)512 * 128 * 2);
    ushort16* WHp  = (ushort16*)alloc((size_t)128 * 128 * 2);
    ushort16* B0 = (ushort16*)alloc((size_t)N * 128 * 2);
    ushort16* B1 = (ushort16*)alloc((size_t)N * 128 * 2);
    ushort16* B2 = (ushort16*)alloc((size_t)N * 128 * 2);
    ushort16* B3 = (ushort16*)alloc((size_t)N * 128 * 2);
    ushort16* B4 = (ushort16*)alloc((size_t)N * 128 * 2);

    hipMemsetAsync(deg8, 0, (size_t)N * 4 * NXCD, stream);
    hipMemsetAsync(cnt8, 0, (size_t)N * 4 * NXCD, stream);

    const int eb = (E + 255) / 256;
    const int nb = (N + 255) / 256;
    const int pb = (N + 3) / 4;          // wave-per-node, 4 waves/block
    const int gb = (N + 127) / 128;      // 128 rows/block MFMA tiles
    const int nblk = (N + 1023) / 1024;  // 49 for N=50000 (<= 64 required)
    const int cb = (N * 64 + 1023) / 1024;

    k_deg_cnt<<<eb, 256, 0, stream>>>(src, dst, ew, deg8, cnt8, pos, E, N);
    k_scan_blk<<<nblk, 256, 0, stream>>>(cnt8, row_ptr, blk_sums, N);
    k_scan_top<<<1, 64, 0, stream>>>(blk_sums, row_ptr, nblk, N);
    k_fix_dis<<<nb, 256, 0, stream>>>(row_ptr, blk_sums, cnt8, base8, deg8, dis, N);
    k_scatter<<<eb, 256, 0, stream>>>(src, dst, ew, dis, base8, pos, csr, E, N);
    k_concat_bf16<<<cb, 256, 0, stream>>>(x, pe, (uint32*)B0, N);
    k_pack_all<<<(16384 + 2048 + 255) / 256, 256, 0, stream>>>(W1, W2, Wmu, Wlv, W1p, W2p, WHp);

    // layer 1: Y1=P*B0, Y2=P*Y1, Y3=P*Y2 -> gemm(transformed W1) -> relu -> B4
    k_prop<<<pb, 256, 0, stream>>>((uint32*)B0, csr, row_ptr, (uint32*)B1, N);
    k_prop<<<pb, 256, 0, stream>>>((uint32*)B1, csr, row_ptr, (uint32*)B2, N);
    k_prop<<<pb, 256, 0, stream>>>((uint32*)B2, csr, row_ptr, (uint32*)B3, N);
    k_mfma_gemm512<true><<<gb, 256, 0, stream>>>(B0, B1, B2, B3, W1p, b1, B4, N);

    // layer 2: Y1=P*B4, Y2, Y3 -> gemm(transformed W2) -> relu -> B3
    k_prop<<<pb, 256, 0, stream>>>((uint32*)B4, csr, row_ptr, (uint32*)B0, N);
    k_prop<<<pb, 256, 0, stream>>>((uint32*)B0, csr, row_ptr, (uint32*)B1, N);
    k_prop<<<pb, 256, 0, stream>>>((uint32*)B1, csr, row_ptr, (uint32*)B2, N);
    k_mfma_gemm512<true><<<gb, 256, 0, stream>>>(B4, B0, B1, B2, W2p, b2, B3, N);

    // heads -> d_out = [mu ; logvar] fp32
    k_mfma_head<<<gb, 256, 0, stream>>>(B3, WHp, bmu, blv, (float*)d_out, N);
}

// Round 8
// 313.213 us; speedup vs baseline: 1.0547x; 1.0037x over previous
//
#include <hip/hip_runtime.h>

// ---------------------------------------------------------------------------
// SpectralEncoder: ChebConv(K=4) x2 + mu/logvar heads.  bf16 features, MFMA
// GEMMs, folded Chebyshev weights.
// R7: revert R6 XCD-sharding (null; recovers shard overhead). New dual-edge
//     prop: half-wave per edge, uint2 (8B) gathers -> ~5.5 wave-inst/edge
//     (vs 7) and half the VMEM ops; 16 edges in flight.
// ---------------------------------------------------------------------------

typedef __bf16 bf16x8 __attribute__((ext_vector_type(8)));
typedef float f32x4 __attribute__((ext_vector_type(4)));
typedef unsigned int uint32;
typedef unsigned short ushort16;

__device__ inline ushort16 f2bf(float f) {            // RNE fp32 -> bf16
    uint32 x = __float_as_uint(f);
    uint32 r = x + 0x7fffu + ((x >> 16) & 1u);
    return (ushort16)(r >> 16);
}
__device__ inline float bflo(uint32 v) { return __uint_as_float(v << 16); }
__device__ inline float bfhi(uint32 v) { return __uint_as_float(v & 0xffff0000u); }

// ---------------- graph preprocessing --------------------------------------

__global__ void k_deg_cnt(const int* __restrict__ src, const int* __restrict__ dst,
                          const float* __restrict__ ew, float* __restrict__ deg,
                          int* __restrict__ cnt, int* __restrict__ pos, int E) {
    int e = blockIdx.x * blockDim.x + threadIdx.x;
    if (e >= E) return;
    atomicAdd(&deg[src[e]], ew[e]);
    pos[e] = atomicAdd(&cnt[dst[e]], 1);
}

// --- scan phase A: 256 thr/block scan 1024 elems, local prefixes + total ---
__global__ void k_scan_blk(const int* __restrict__ cnt, int* __restrict__ row_ptr,
                           int* __restrict__ blk_sums, int N) {
    __shared__ int wsum[4];
    const int tid = threadIdx.x;
    const int base = blockIdx.x * 1024 + tid * 4;
    int4 v = make_int4(0, 0, 0, 0);
    if (base + 3 < N) v = *(const int4*)&cnt[base];
    else {
        if (base + 0 < N) v.x = cnt[base + 0];
        if (base + 1 < N) v.y = cnt[base + 1];
        if (base + 2 < N) v.z = cnt[base + 2];
    }
    const int tsum = v.x + v.y + v.z + v.w;
    const int lane = tid & 63;
    const int wv = tid >> 6;
    int incl = tsum;
    #pragma unroll
    for (int off = 1; off < 64; off <<= 1) {
        int t = __shfl_up(incl, off);
        if (lane >= off) incl += t;
    }
    if (lane == 63) wsum[wv] = incl;
    __syncthreads();
    int woff = 0;
    #pragma unroll
    for (int w = 0; w < 4; ++w) if (w < wv) woff += wsum[w];
    const int excl = woff + incl - tsum;
    if (base + 0 < N) row_ptr[base + 0] = excl;
    if (base + 1 < N) row_ptr[base + 1] = excl + v.x;
    if (base + 2 < N) row_ptr[base + 2] = excl + v.x + v.y;
    if (base + 3 < N) row_ptr[base + 3] = excl + v.x + v.y + v.z;
    if (tid == 255) blk_sums[blockIdx.x] = woff + incl;
}

// --- scan phase B: one wave scans block totals (nblk <= 64) ----------------
__global__ void k_scan_top(int* __restrict__ blk_sums, int* __restrict__ row_ptr,
                           int nblk, int N) {
    const int lane = threadIdx.x;
    int v = (lane < nblk) ? blk_sums[lane] : 0;
    int incl = v;
    #pragma unroll
    for (int off = 1; off < 64; off <<= 1) {
        int t = __shfl_up(incl, off);
        if (lane >= off) incl += t;
    }
    if (lane < nblk) blk_sums[lane] = incl - v;
    if (lane == 63) row_ptr[N] = incl;
}

// --- scan phase C fused with dis = rsqrt(deg) ------------------------------
__global__ void k_fix_dis(int* __restrict__ row_ptr, const int* __restrict__ blk_sums,
                          const float* __restrict__ deg, float* __restrict__ dis, int N) {
    int i = blockIdx.x * blockDim.x + threadIdx.x;
    if (i >= N) return;
    row_ptr[i] += blk_sums[i >> 10];
    float d = deg[i];
    dis[i] = d > 0.f ? rsqrtf(fmaxf(d, 1e-12f)) : 0.f;
}

// --- atomic-free scatter: csr[row_ptr[dst]+pos] = {src, w_bits} ------------
__global__ void k_scatter(const int* __restrict__ src, const int* __restrict__ dst,
                          const float* __restrict__ ew, const float* __restrict__ dis,
                          const int* __restrict__ row_ptr, const int* __restrict__ pos,
                          int2* __restrict__ csr, int E) {
    int e = blockIdx.x * blockDim.x + threadIdx.x;
    if (e >= E) return;
    int s = src[e], d = dst[e];
    float wv = -dis[s] * ew[e] * dis[d];
    csr[row_ptr[d] + pos[e]] = make_int2(s, __float_as_int(wv));
}

// ---------------- feature concat -> bf16 (8 feats/thread) ------------------

__global__ void k_concat_bf16(const float* __restrict__ x, const float* __restrict__ pe,
                              uint32* __restrict__ h, int N) {
    int i4 = (blockIdx.x * blockDim.x + threadIdx.x) * 4;  // 4 uint32 pairs
    if (i4 >= N * 64) return;
    int node = i4 >> 6, p = i4 & 63;      // chunk never crosses node/x-pe bound
    float4 fa, fb;
    if (p < 56) {
        const float* xp = &x[(size_t)node * 112 + p * 2];
        fa = *(const float4*)xp; fb = *(const float4*)(xp + 4);
    } else {
        const float* pp = &pe[(size_t)node * 16 + (p - 56) * 2];
        fa = *(const float4*)pp; fb = *(const float4*)(pp + 4);
    }
    int4 o;
    o.x = (uint32)f2bf(fa.x) | ((uint32)f2bf(fa.y) << 16);
    o.y = (uint32)f2bf(fa.z) | ((uint32)f2bf(fa.w) << 16);
    o.z = (uint32)f2bf(fb.x) | ((uint32)f2bf(fb.y) << 16);
    o.w = (uint32)f2bf(fb.z) | ((uint32)f2bf(fb.w) << 16);
    *(int4*)&h[i4] = o;
}

// ---------------- weight packing (fused, recurrence-transformed) -----------
// Layer transform (exact fp32): out = h(W0-W2) + Ph(W1-3W3) + P^2h(2W2) + P^3h(4W3)
// B-frag (16x16x32): lane l holds B[k=(l>>4)*8+j][col], j=0..7.

__device__ inline float wtrans(const float* __restrict__ W, int kb, size_t o) {
    switch (kb) {
        case 0:  return W[o] - W[o + 32768];
        case 1:  return W[o + 16384] - 3.f * W[o + 49152];
        case 2:  return 2.f * W[o + 32768];
        default: return 4.f * W[o + 49152];
    }
}

__global__ void k_pack_all(const float* __restrict__ W1, const float* __restrict__ W2,
                           const float* __restrict__ Wm, const float* __restrict__ Wl,
                           ushort16* __restrict__ W1p, ushort16* __restrict__ W2p,
                           ushort16* __restrict__ WHp) {
    int t = blockIdx.x * blockDim.x + threadIdx.x;
    uint32 v[8];
    if (t < 16384) {   // layer packs: 2 x 16 ks x 8 c x 64 lanes
        const float* W = (t < 8192) ? W1 : W2;
        ushort16* Wp = (t < 8192) ? W1p : W2p;
        int tt = t & 8191;
        int l = tt & 63, c = (tt >> 6) & 7, ks = tt >> 9;
        int kb = ks >> 2;
        int r0 = (ks & 3) * 32 + (l >> 4) * 8;
        int col = c * 16 + (l & 15);
        #pragma unroll
        for (int j = 0; j < 8; ++j)
            v[j] = f2bf(wtrans(W, kb, (size_t)(r0 + j) * 128 + col));
        uint4 o;
        o.x = v[0] | (v[1] << 16); o.y = v[2] | (v[3] << 16);
        o.z = v[4] | (v[5] << 16); o.w = v[6] | (v[7] << 16);
        *(uint4*)(Wp + (size_t)tt * 8) = o;
    } else if (t < 16384 + 2048) {   // head pack: cols = [mu | lv]
        int tt = t - 16384;
        int l = tt & 63, c = (tt >> 6) & 7, ks = tt >> 9;
        int k0 = ks * 32 + (l >> 4) * 8;
        int cc = c * 16 + (l & 15);
        const float* Ws = (cc < 64) ? Wm : Wl;
        int col = cc & 63;
        #pragma unroll
        for (int j = 0; j < 8; ++j) v[j] = f2bf(Ws[(size_t)(k0 + j) * 64 + col]);
        uint4 o;
        o.x = v[0] | (v[1] << 16); o.y = v[2] | (v[3] << 16);
        o.z = v[4] | (v[5] << 16); o.w = v[6] | (v[7] << 16);
        *(uint4*)(WHp + (size_t)tt * 8) = o;
    }
}

// ---------------- dual-edge gather prop: out = P * tin ---------------------
// one wave per node; lanes 0-31 take even edges, 32-63 odd edges; each lane
// loads uint2 (4 bf16) of its half-row -> one wave-load covers 2 edge-rows.
// Cross-half combine via shfl_xor(32); lanes 0-31 store the 256B row.

__global__ void k_prop(const uint32* __restrict__ tin, const int2* __restrict__ csr,
                       const int* __restrict__ row_ptr, uint32* __restrict__ out, int N) {
    int wid = (blockIdx.x * blockDim.x + threadIdx.x) >> 6;
    int lane = threadIdx.x & 63;
    if (wid >= N) return;
    int beg = row_ptr[wid], end = row_ptr[wid + 1];
    const int half = lane >> 5;          // which edge of each pair
    const int fl = lane & 31;            // feature-quad group: feats [fl*4, fl*4+4)
    float a0 = 0.f, a1 = 0.f, a2 = 0.f, a3 = 0.f;
    for (int base = beg; base < end; base += 64) {
        int m = end - base; if (m > 64) m = 64;
        int2 ev = (lane < m) ? csr[base + lane] : make_int2(0, 0);  // pad w=0
        for (int j = 0; j < m; j += 8) {        // 4 pairs (8 edges) in flight
            #pragma unroll
            for (int u = 0; u < 4; ++u) {
                int idx = j + u * 2 + half;     // < 64 always; pads give w=0
                int s = __shfl(ev.x, idx);
                float w = __uint_as_float(__shfl(ev.y, idx));
                uint2 v = *(const uint2*)&tin[(size_t)s * 64 + fl * 2];
                a0 = fmaf(w, bflo(v.x), a0); a1 = fmaf(w, bfhi(v.x), a1);
                a2 = fmaf(w, bflo(v.y), a2); a3 = fmaf(w, bfhi(v.y), a3);
            }
        }
    }
    a0 += __shfl_xor(a0, 32);
    a1 += __shfl_xor(a1, 32);
    a2 += __shfl_xor(a2, 32);
    a3 += __shfl_xor(a3, 32);
    if (lane < 32) {
        uint2 o;
        o.x = (uint32)f2bf(a0) | ((uint32)f2bf(a1) << 16);
        o.y = (uint32)f2bf(a2) | ((uint32)f2bf(a3) << 16);
        *(uint2*)&out[(size_t)wid * 64 + fl * 2] = o;
    }
}

// ---------------- MFMA GEMM: C[N,128] = relu(sum_t T_t @ W_t + b), K=512 ---

template<bool RELU>
__launch_bounds__(256)
__global__ void k_mfma_gemm512(const ushort16* __restrict__ t0, const ushort16* __restrict__ t1,
                               const ushort16* __restrict__ t2, const ushort16* __restrict__ t3,
                               const ushort16* __restrict__ Wp, const float* __restrict__ bias,
                               ushort16* __restrict__ C, int N) {
    const int lane = threadIdx.x & 63;
    const int wave = threadIdx.x >> 6;
    const int brow = blockIdx.x * 128 + wave * 32;
    int r0 = brow + (lane & 15);
    int r1 = r0 + 16;
    if (r0 >= N) r0 = N - 1;
    if (r1 >= N) r1 = N - 1;
    const int kg8 = (lane >> 4) * 8;
    f32x4 acc[2][8] = {};
    #pragma unroll
    for (int t = 0; t < 4; ++t) {
        const ushort16* __restrict__ A = (t == 0) ? t0 : (t == 1) ? t1 : (t == 2) ? t2 : t3;
        const ushort16* a0p = A + (size_t)r0 * 128 + kg8;
        const ushort16* a1p = A + (size_t)r1 * 128 + kg8;
        #pragma unroll
        for (int ks2 = 0; ks2 < 4; ++ks2) {
            bf16x8 a0 = *(const bf16x8*)(a0p + ks2 * 32);
            bf16x8 a1 = *(const bf16x8*)(a1p + ks2 * 32);
            const ushort16* bp = Wp + (size_t)((t * 4 + ks2) * 8 * 64 + lane) * 8;
            #pragma unroll
            for (int c = 0; c < 8; ++c) {
                bf16x8 b = *(const bf16x8*)(bp + c * 512);
                acc[0][c] = __builtin_amdgcn_mfma_f32_16x16x32_bf16(a0, b, acc[0][c], 0, 0, 0);
                acc[1][c] = __builtin_amdgcn_mfma_f32_16x16x32_bf16(a1, b, acc[1][c], 0, 0, 0);
            }
        }
    }
    const int col0 = lane & 15;
    const int rj = (lane >> 4) * 4;
    #pragma unroll
    for (int m = 0; m < 2; ++m) {
        #pragma unroll
        for (int c = 0; c < 8; ++c) {
            float bv = bias[c * 16 + col0];
            #pragma unroll
            for (int j = 0; j < 4; ++j) {
                int row = brow + m * 16 + rj + j;
                if (row < N) {
                    float v = acc[m][c][j] + bv;
                    if (RELU) v = fmaxf(v, 0.f);
                    C[(size_t)row * 128 + c * 16 + col0] = f2bf(v);
                }
            }
        }
    }
}

// ---------------- fused heads via MFMA: [N,128]@[128,128], cols=[mu|lv] ----

__launch_bounds__(256)
__global__ void k_mfma_head(const ushort16* __restrict__ A, const ushort16* __restrict__ Wp,
                            const float* __restrict__ bm, const float* __restrict__ bl,
                            float* __restrict__ out, int N) {
    const int lane = threadIdx.x & 63;
    const int wave = threadIdx.x >> 6;
    const int brow = blockIdx.x * 128 + wave * 32;
    int r0 = brow + (lane & 15);
    int r1 = r0 + 16;
    if (r0 >= N) r0 = N - 1;
    if (r1 >= N) r1 = N - 1;
    const int kg8 = (lane >> 4) * 8;
    f32x4 acc[2][8] = {};
    const ushort16* a0p = A + (size_t)r0 * 128 + kg8;
    const ushort16* a1p = A + (size_t)r1 * 128 + kg8;
    #pragma unroll
    for (int ks = 0; ks < 4; ++ks) {
        bf16x8 a0 = *(const bf16x8*)(a0p + ks * 32);
        bf16x8 a1 = *(const bf16x8*)(a1p + ks * 32);
        const ushort16* bp = Wp + (size_t)(ks * 8 * 64 + lane) * 8;
        #pragma unroll
        for (int c = 0; c < 8; ++c) {
            bf16x8 b = *(const bf16x8*)(bp + c * 512);
            acc[0][c] = __builtin_amdgcn_mfma_f32_16x16x32_bf16(a0, b, acc[0][c], 0, 0, 0);
            acc[1][c] = __builtin_amdgcn_mfma_f32_16x16x32_bf16(a1, b, acc[1][c], 0, 0, 0);
        }
    }
    const int col0 = lane & 15;
    const int rj = (lane >> 4) * 4;
    #pragma unroll
    for (int m = 0; m < 2; ++m) {
        #pragma unroll
        for (int c = 0; c < 8; ++c) {
            int gcol = (c & 3) * 16 + col0;
            float bv = (c < 4) ? bm[gcol] : bl[gcol];
            size_t hoff = (c < 4) ? 0 : (size_t)N * 64;
            #pragma unroll
            for (int j = 0; j < 4; ++j) {
                int row = brow + m * 16 + rj + j;
                if (row < N)
                    out[hoff + (size_t)row * 64 + gcol] = acc[m][c][j] + bv;
            }
        }
    }
}

// ---------------------------------------------------------------------------

extern "C" void kernel_launch(void* const* d_in, const int* in_sizes, int n_in,
                              void* d_out, int out_size, void* d_ws, size_t ws_size,
                              hipStream_t stream) {
    const float* x   = (const float*)d_in[0];
    const int*   ei  = (const int*)d_in[1];
    const float* pe  = (const float*)d_in[2];
    const float* ew  = (const float*)d_in[3];
    const float* W1  = (const float*)d_in[4];
    const float* b1  = (const float*)d_in[5];
    const float* W2  = (const float*)d_in[6];
    const float* b2  = (const float*)d_in[7];
    const float* Wmu = (const float*)d_in[8];
    const float* bmu = (const float*)d_in[9];
    const float* Wlv = (const float*)d_in[10];
    const float* blv = (const float*)d_in[11];

    const int N = in_sizes[0] / 112;
    const int E = in_sizes[1] / 2;
    const int* src = ei;
    const int* dst = ei + E;

    char* ws = (char*)d_ws;
    size_t off = 0;
    auto alloc = [&](size_t bytes) -> char* {
        char* p = ws + off;
        off = (off + bytes + 255) & ~(size_t)255;
        return p;
    };
    float* deg     = (float*)alloc((size_t)N * 4);
    int*   cnt     = (int*)  alloc((size_t)N * 4);
    float* dis     = (float*)alloc((size_t)N * 4);
    int*   row_ptr = (int*)  alloc((size_t)(N + 1) * 4);
    int*   blk_sums= (int*)  alloc((size_t)256 * 4);
    int*   pos     = (int*)  alloc((size_t)E * 4);
    int2*  csr     = (int2*) alloc((size_t)E * 8);
    ushort16* W1p  = (ushort16*)alloc((size_t)512 * 128 * 2);
    ushort16* W2p  = (ushort16*)alloc((size_t)512 * 128 * 2);
    ushort16* WHp  = (ushort16*)alloc((size_t)128 * 128 * 2);
    ushort16* B0 = (ushort16*)alloc((size_t)N * 128 * 2);
    ushort16* B1 = (ushort16*)alloc((size_t)N * 128 * 2);
    ushort16* B2 = (ushort16*)alloc((size_t)N * 128 * 2);
    ushort16* B3 = (ushort16*)alloc((size_t)N * 128 * 2);
    ushort16* B4 = (ushort16*)alloc((size_t)N * 128 * 2);

    hipMemsetAsync(deg, 0, (size_t)N * 4, stream);
    hipMemsetAsync(cnt, 0, (size_t)N * 4, stream);

    const int eb = (E + 255) / 256;
    const int nb = (N + 255) / 256;
    const int pb = (N + 3) / 4;          // wave-per-node, 4 waves/block
    const int gb = (N + 127) / 128;      // 128 rows/block MFMA tiles
    const int nblk = (N + 1023) / 1024;  // 49 for N=50000 (<= 64 required)
    const int cb = (N * 64 + 1023) / 1024;

    k_deg_cnt<<<eb, 256, 0, stream>>>(src, dst, ew, deg, cnt, pos, E);
    k_scan_blk<<<nblk, 256, 0, stream>>>(cnt, row_ptr, blk_sums, N);
    k_scan_top<<<1, 64, 0, stream>>>(blk_sums, row_ptr, nblk, N);
    k_fix_dis<<<nb, 256, 0, stream>>>(row_ptr, blk_sums, deg, dis, N);
    k_scatter<<<eb, 256, 0, stream>>>(src, dst, ew, dis, row_ptr, pos, csr, E);
    k_concat_bf16<<<cb, 256, 0, stream>>>(x, pe, (uint32*)B0, N);
    k_pack_all<<<(16384 + 2048 + 255) / 256, 256, 0, stream>>>(W1, W2, Wmu, Wlv, W1p, W2p, WHp);

    // layer 1: Y1=P*B0, Y2=P*Y1, Y3=P*Y2 -> gemm(transformed W1) -> relu -> B4
    k_prop<<<pb, 256, 0, stream>>>((uint32*)B0, csr, row_ptr, (uint32*)B1, N);
    k_prop<<<pb, 256, 0, stream>>>((uint32*)B1, csr, row_ptr, (uint32*)B2, N);
    k_prop<<<pb, 256, 0, stream>>>((uint32*)B2, csr, row_ptr, (uint32*)B3, N);
    k_mfma_gemm512<true><<<gb, 256, 0, stream>>>(B0, B1, B2, B3, W1p, b1, B4, N);

    // layer 2: Y1=P*B4, Y2, Y3 -> gemm(transformed W2) -> relu -> B3
    k_prop<<<pb, 256, 0, stream>>>((uint32*)B4, csr, row_ptr, (uint32*)B0, N);
    k_prop<<<pb, 256, 0, stream>>>((uint32*)B0, csr, row_ptr, (uint32*)B1, N);
    k_prop<<<pb, 256, 0, stream>>>((uint32*)B1, csr, row_ptr, (uint32*)B2, N);
    k_mfma_gemm512<true><<<gb, 256, 0, stream>>>(B4, B0, B1, B2, W2p, b2, B3, N);

    // heads -> d_out = [mu ; logvar] fp32
    k_mfma_head<<<gb, 256, 0, stream>>>(B3, WHp, bmu, blv, (float*)d_out, N);
}

// Round 9
// 312.022 us; speedup vs baseline: 1.0587x; 1.0038x over previous
//
#include <hip/hip_runtime.h>

// ---------------------------------------------------------------------------
// SpectralEncoder: ChebConv(K=4) x2 + mu/logvar heads.  bf16 features, MFMA
// GEMMs, folded Chebyshev weights.
// R8: (a) deg_cnt split into 4 quarter dispatches for top-5 visibility;
//     (b) prop = 2 nodes/wave (half-wave per node, full 128-feat row per
//     half, per-half edge broadcast) -> 2 independent memory chains/wave.
// ---------------------------------------------------------------------------

typedef __bf16 bf16x8 __attribute__((ext_vector_type(8)));
typedef float f32x4 __attribute__((ext_vector_type(4)));
typedef unsigned int uint32;
typedef unsigned short ushort16;

__device__ inline ushort16 f2bf(float f) {            // RNE fp32 -> bf16
    uint32 x = __float_as_uint(f);
    uint32 r = x + 0x7fffu + ((x >> 16) & 1u);
    return (ushort16)(r >> 16);
}
__device__ inline float bflo(uint32 v) { return __uint_as_float(v << 16); }
__device__ inline float bfhi(uint32 v) { return __uint_as_float(v & 0xffff0000u); }

// ---------------- graph preprocessing --------------------------------------
// quarter-range atomic kernel (launched 4x for profiler visibility)

__global__ void k_deg_cnt(const int* __restrict__ src, const int* __restrict__ dst,
                          const float* __restrict__ ew, float* __restrict__ deg,
                          int* __restrict__ cnt, int* __restrict__ pos,
                          int e0, int e1) {
    int e = e0 + blockIdx.x * blockDim.x + threadIdx.x;
    if (e >= e1) return;
    atomicAdd(&deg[src[e]], ew[e]);
    pos[e] = atomicAdd(&cnt[dst[e]], 1);
}

// --- scan phase A: 256 thr/block scan 1024 elems, local prefixes + total ---
__global__ void k_scan_blk(const int* __restrict__ cnt, int* __restrict__ row_ptr,
                           int* __restrict__ blk_sums, int N) {
    __shared__ int wsum[4];
    const int tid = threadIdx.x;
    const int base = blockIdx.x * 1024 + tid * 4;
    int4 v = make_int4(0, 0, 0, 0);
    if (base + 3 < N) v = *(const int4*)&cnt[base];
    else {
        if (base + 0 < N) v.x = cnt[base + 0];
        if (base + 1 < N) v.y = cnt[base + 1];
        if (base + 2 < N) v.z = cnt[base + 2];
    }
    const int tsum = v.x + v.y + v.z + v.w;
    const int lane = tid & 63;
    const int wv = tid >> 6;
    int incl = tsum;
    #pragma unroll
    for (int off = 1; off < 64; off <<= 1) {
        int t = __shfl_up(incl, off);
        if (lane >= off) incl += t;
    }
    if (lane == 63) wsum[wv] = incl;
    __syncthreads();
    int woff = 0;
    #pragma unroll
    for (int w = 0; w < 4; ++w) if (w < wv) woff += wsum[w];
    const int excl = woff + incl - tsum;
    if (base + 0 < N) row_ptr[base + 0] = excl;
    if (base + 1 < N) row_ptr[base + 1] = excl + v.x;
    if (base + 2 < N) row_ptr[base + 2] = excl + v.x + v.y;
    if (base + 3 < N) row_ptr[base + 3] = excl + v.x + v.y + v.z;
    if (tid == 255) blk_sums[blockIdx.x] = woff + incl;
}

// --- scan phase B: one wave scans block totals (nblk <= 64) ----------------
__global__ void k_scan_top(int* __restrict__ blk_sums, int* __restrict__ row_ptr,
                           int nblk, int N) {
    const int lane = threadIdx.x;
    int v = (lane < nblk) ? blk_sums[lane] : 0;
    int incl = v;
    #pragma unroll
    for (int off = 1; off < 64; off <<= 1) {
        int t = __shfl_up(incl, off);
        if (lane >= off) incl += t;
    }
    if (lane < nblk) blk_sums[lane] = incl - v;
    if (lane == 63) row_ptr[N] = incl;
}

// --- scan phase C fused with dis = rsqrt(deg) ------------------------------
__global__ void k_fix_dis(int* __restrict__ row_ptr, const int* __restrict__ blk_sums,
                          const float* __restrict__ deg, float* __restrict__ dis, int N) {
    int i = blockIdx.x * blockDim.x + threadIdx.x;
    if (i >= N) return;
    row_ptr[i] += blk_sums[i >> 10];
    float d = deg[i];
    dis[i] = d > 0.f ? rsqrtf(fmaxf(d, 1e-12f)) : 0.f;
}

// --- atomic-free scatter: csr[row_ptr[dst]+pos] = {src, w_bits} ------------
__global__ void k_scatter(const int* __restrict__ src, const int* __restrict__ dst,
                          const float* __restrict__ ew, const float* __restrict__ dis,
                          const int* __restrict__ row_ptr, const int* __restrict__ pos,
                          int2* __restrict__ csr, int E) {
    int e = blockIdx.x * blockDim.x + threadIdx.x;
    if (e >= E) return;
    int s = src[e], d = dst[e];
    float wv = -dis[s] * ew[e] * dis[d];
    csr[row_ptr[d] + pos[e]] = make_int2(s, __float_as_int(wv));
}

// ---------------- feature concat -> bf16 (8 feats/thread) ------------------

__global__ void k_concat_bf16(const float* __restrict__ x, const float* __restrict__ pe,
                              uint32* __restrict__ h, int N) {
    int i4 = (blockIdx.x * blockDim.x + threadIdx.x) * 4;  // 4 uint32 pairs
    if (i4 >= N * 64) return;
    int node = i4 >> 6, p = i4 & 63;      // chunk never crosses node/x-pe bound
    float4 fa, fb;
    if (p < 56) {
        const float* xp = &x[(size_t)node * 112 + p * 2];
        fa = *(const float4*)xp; fb = *(const float4*)(xp + 4);
    } else {
        const float* pp = &pe[(size_t)node * 16 + (p - 56) * 2];
        fa = *(const float4*)pp; fb = *(const float4*)(pp + 4);
    }
    int4 o;
    o.x = (uint32)f2bf(fa.x) | ((uint32)f2bf(fa.y) << 16);
    o.y = (uint32)f2bf(fa.z) | ((uint32)f2bf(fa.w) << 16);
    o.z = (uint32)f2bf(fb.x) | ((uint32)f2bf(fb.y) << 16);
    o.w = (uint32)f2bf(fb.z) | ((uint32)f2bf(fb.w) << 16);
    *(int4*)&h[i4] = o;
}

// ---------------- weight packing (fused, recurrence-transformed) -----------
// Layer transform (exact fp32): out = h(W0-W2) + Ph(W1-3W3) + P^2h(2W2) + P^3h(4W3)
// B-frag (16x16x32): lane l holds B[k=(l>>4)*8+j][col], j=0..7.

__device__ inline float wtrans(const float* __restrict__ W, int kb, size_t o) {
    switch (kb) {
        case 0:  return W[o] - W[o + 32768];
        case 1:  return W[o + 16384] - 3.f * W[o + 49152];
        case 2:  return 2.f * W[o + 32768];
        default: return 4.f * W[o + 49152];
    }
}

__global__ void k_pack_all(const float* __restrict__ W1, const float* __restrict__ W2,
                           const float* __restrict__ Wm, const float* __restrict__ Wl,
                           ushort16* __restrict__ W1p, ushort16* __restrict__ W2p,
                           ushort16* __restrict__ WHp) {
    int t = blockIdx.x * blockDim.x + threadIdx.x;
    uint32 v[8];
    if (t < 16384) {   // layer packs: 2 x 16 ks x 8 c x 64 lanes
        const float* W = (t < 8192) ? W1 : W2;
        ushort16* Wp = (t < 8192) ? W1p : W2p;
        int tt = t & 8191;
        int l = tt & 63, c = (tt >> 6) & 7, ks = tt >> 9;
        int kb = ks >> 2;
        int r0 = (ks & 3) * 32 + (l >> 4) * 8;
        int col = c * 16 + (l & 15);
        #pragma unroll
        for (int j = 0; j < 8; ++j)
            v[j] = f2bf(wtrans(W, kb, (size_t)(r0 + j) * 128 + col));
        uint4 o;
        o.x = v[0] | (v[1] << 16); o.y = v[2] | (v[3] << 16);
        o.z = v[4] | (v[5] << 16); o.w = v[6] | (v[7] << 16);
        *(uint4*)(Wp + (size_t)tt * 8) = o;
    } else if (t < 16384 + 2048) {   // head pack: cols = [mu | lv]
        int tt = t - 16384;
        int l = tt & 63, c = (tt >> 6) & 7, ks = tt >> 9;
        int k0 = ks * 32 + (l >> 4) * 8;
        int cc = c * 16 + (l & 15);
        const float* Ws = (cc < 64) ? Wm : Wl;
        int col = cc & 63;
        #pragma unroll
        for (int j = 0; j < 8; ++j) v[j] = f2bf(Ws[(size_t)(k0 + j) * 64 + col]);
        uint4 o;
        o.x = v[0] | (v[1] << 16); o.y = v[2] | (v[3] << 16);
        o.z = v[4] | (v[5] << 16); o.w = v[6] | (v[7] << 16);
        *(uint4*)(WHp + (size_t)tt * 8) = o;
    }
}

// ---------------- gather prop: 2 nodes per wave ----------------------------
// lanes 0-31 own node 2w, lanes 32-63 own node 2w+1.  Each half-wave covers
// the full 128-feat row (lane fl -> feats [fl*4,fl*4+4), uint2 load), and
// broadcasts its own 32-edge batch via intra-half shfl.  Two independent
// gather chains per wave -> 2x memory-level parallelism at fixed occupancy.

__global__ void k_prop(const uint32* __restrict__ tin, const int2* __restrict__ csr,
                       const int* __restrict__ row_ptr, uint32* __restrict__ out, int N) {
    int wave = (blockIdx.x * blockDim.x + threadIdx.x) >> 6;
    int lane = threadIdx.x & 63;
    const int half = lane >> 5;
    const int fl = lane & 31;
    int node = wave * 2 + half;
    bool valid = node < N;
    if (!valid) node = N - 1;
    int beg = row_ptr[node];
    int m = valid ? (row_ptr[node + 1] - beg) : 0;   // per-half degree
    float a0 = 0.f, a1 = 0.f, a2 = 0.f, a3 = 0.f;
    for (int base = 0; base < m; base += 32) {       // half-uniform trip count
        int rem = m - base; if (rem > 32) rem = 32;
        int2 ev = (fl < rem) ? csr[beg + base + fl] : make_int2(0, 0);  // pad w=0
        for (int j = 0; j < rem; j += 8) {
            #pragma unroll
            for (int u = 0; u < 8; ++u) {            // pads give w=0
                int s = __shfl(ev.x, half * 32 + j + u);
                float w = __uint_as_float(__shfl(ev.y, half * 32 + j + u));
                uint2 v = *(const uint2*)&tin[(size_t)s * 64 + fl * 2];
                a0 = fmaf(w, bflo(v.x), a0); a1 = fmaf(w, bfhi(v.x), a1);
                a2 = fmaf(w, bflo(v.y), a2); a3 = fmaf(w, bfhi(v.y), a3);
            }
        }
    }
    if (valid) {
        uint2 o;
        o.x = (uint32)f2bf(a0) | ((uint32)f2bf(a1) << 16);
        o.y = (uint32)f2bf(a2) | ((uint32)f2bf(a3) << 16);
        *(uint2*)&out[(size_t)node * 64 + fl * 2] = o;
    }
}

// ---------------- MFMA GEMM: C[N,128] = relu(sum_t T_t @ W_t + b), K=512 ---

template<bool RELU>
__launch_bounds__(256)
__global__ void k_mfma_gemm512(const ushort16* __restrict__ t0, const ushort16* __restrict__ t1,
                               const ushort16* __restrict__ t2, const ushort16* __restrict__ t3,
                               const ushort16* __restrict__ Wp, const float* __restrict__ bias,
                               ushort16* __restrict__ C, int N) {
    const int lane = threadIdx.x & 63;
    const int wave = threadIdx.x >> 6;
    const int brow = blockIdx.x * 128 + wave * 32;
    int r0 = brow + (lane & 15);
    int r1 = r0 + 16;
    if (r0 >= N) r0 = N - 1;
    if (r1 >= N) r1 = N - 1;
    const int kg8 = (lane >> 4) * 8;
    f32x4 acc[2][8] = {};
    #pragma unroll
    for (int t = 0; t < 4; ++t) {
        const ushort16* __restrict__ A = (t == 0) ? t0 : (t == 1) ? t1 : (t == 2) ? t2 : t3;
        const ushort16* a0p = A + (size_t)r0 * 128 + kg8;
        const ushort16* a1p = A + (size_t)r1 * 128 + kg8;
        #pragma unroll
        for (int ks2 = 0; ks2 < 4; ++ks2) {
            bf16x8 a0 = *(const bf16x8*)(a0p + ks2 * 32);
            bf16x8 a1 = *(const bf16x8*)(a1p + ks2 * 32);
            const ushort16* bp = Wp + (size_t)((t * 4 + ks2) * 8 * 64 + lane) * 8;
            #pragma unroll
            for (int c = 0; c < 8; ++c) {
                bf16x8 b = *(const bf16x8*)(bp + c * 512);
                acc[0][c] = __builtin_amdgcn_mfma_f32_16x16x32_bf16(a0, b, acc[0][c], 0, 0, 0);
                acc[1][c] = __builtin_amdgcn_mfma_f32_16x16x32_bf16(a1, b, acc[1][c], 0, 0, 0);
            }
        }
    }
    const int col0 = lane & 15;
    const int rj = (lane >> 4) * 4;
    #pragma unroll
    for (int m = 0; m < 2; ++m) {
        #pragma unroll
        for (int c = 0; c < 8; ++c) {
            float bv = bias[c * 16 + col0];
            #pragma unroll
            for (int j = 0; j < 4; ++j) {
                int row = brow + m * 16 + rj + j;
                if (row < N) {
                    float v = acc[m][c][j] + bv;
                    if (RELU) v = fmaxf(v, 0.f);
                    C[(size_t)row * 128 + c * 16 + col0] = f2bf(v);
                }
            }
        }
    }
}

// ---------------- fused heads via MFMA: [N,128]@[128,128], cols=[mu|lv] ----

__launch_bounds__(256)
__global__ void k_mfma_head(const ushort16* __restrict__ A, const ushort16* __restrict__ Wp,
                            const float* __restrict__ bm, const float* __restrict__ bl,
                            float* __restrict__ out, int N) {
    const int lane = threadIdx.x & 63;
    const int wave = threadIdx.x >> 6;
    const int brow = blockIdx.x * 128 + wave * 32;
    int r0 = brow + (lane & 15);
    int r1 = r0 + 16;
    if (r0 >= N) r0 = N - 1;
    if (r1 >= N) r1 = N - 1;
    const int kg8 = (lane >> 4) * 8;
    f32x4 acc[2][8] = {};
    const ushort16* a0p = A + (size_t)r0 * 128 + kg8;
    const ushort16* a1p = A + (size_t)r1 * 128 + kg8;
    #pragma unroll
    for (int ks = 0; ks < 4; ++ks) {
        bf16x8 a0 = *(const bf16x8*)(a0p + ks * 32);
        bf16x8 a1 = *(const bf16x8*)(a1p + ks * 32);
        const ushort16* bp = Wp + (size_t)(ks * 8 * 64 + lane) * 8;
        #pragma unroll
        for (int c = 0; c < 8; ++c) {
            bf16x8 b = *(const bf16x8*)(bp + c * 512);
            acc[0][c] = __builtin_amdgcn_mfma_f32_16x16x32_bf16(a0, b, acc[0][c], 0, 0, 0);
            acc[1][c] = __builtin_amdgcn_mfma_f32_16x16x32_bf16(a1, b, acc[1][c], 0, 0, 0);
        }
    }
    const int col0 = lane & 15;
    const int rj = (lane >> 4) * 4;
    #pragma unroll
    for (int m = 0; m < 2; ++m) {
        #pragma unroll
        for (int c = 0; c < 8; ++c) {
            int gcol = (c & 3) * 16 + col0;
            float bv = (c < 4) ? bm[gcol] : bl[gcol];
            size_t hoff = (c < 4) ? 0 : (size_t)N * 64;
            #pragma unroll
            for (int j = 0; j < 4; ++j) {
                int row = brow + m * 16 + rj + j;
                if (row < N)
                    out[hoff + (size_t)row * 64 + gcol] = acc[m][c][j] + bv;
            }
        }
    }
}

// ---------------------------------------------------------------------------

extern "C" void kernel_launch(void* const* d_in, const int* in_sizes, int n_in,
                              void* d_out, int out_size, void* d_ws, size_t ws_size,
                              hipStream_t stream) {
    const float* x   = (const float*)d_in[0];
    const int*   ei  = (const int*)d_in[1];
    const float* pe  = (const float*)d_in[2];
    const float* ew  = (const float*)d_in[3];
    const float* W1  = (const float*)d_in[4];
    const float* b1  = (const float*)d_in[5];
    const float* W2  = (const float*)d_in[6];
    const float* b2  = (const float*)d_in[7];
    const float* Wmu = (const float*)d_in[8];
    const float* bmu = (const float*)d_in[9];
    const float* Wlv = (const float*)d_in[10];
    const float* blv = (const float*)d_in[11];

    const int N = in_sizes[0] / 112;
    const int E = in_sizes[1] / 2;
    const int* src = ei;
    const int* dst = ei + E;

    char* ws = (char*)d_ws;
    size_t off = 0;
    auto alloc = [&](size_t bytes) -> char* {
        char* p = ws + off;
        off = (off + bytes + 255) & ~(size_t)255;
        return p;
    };
    float* deg     = (float*)alloc((size_t)N * 4);
    int*   cnt     = (int*)  alloc((size_t)N * 4);
    float* dis     = (float*)alloc((size_t)N * 4);
    int*   row_ptr = (int*)  alloc((size_t)(N + 1) * 4);
    int*   blk_sums= (int*)  alloc((size_t)256 * 4);
    int*   pos     = (int*)  alloc((size_t)E * 4);
    int2*  csr     = (int2*) alloc((size_t)E * 8);
    ushort16* W1p  = (ushort16*)alloc((size_t)512 * 128 * 2);
    ushort16* W2p  = (ushort16*)alloc((size_t)512 * 128 * 2);
    ushort16* WHp  = (ushort16*)alloc((size_t)128 * 128 * 2);
    ushort16* B0 = (ushort16*)alloc((size_t)N * 128 * 2);
    ushort16* B1 = (ushort16*)alloc((size_t)N * 128 * 2);
    ushort16* B2 = (ushort16*)alloc((size_t)N * 128 * 2);
    ushort16* B3 = (ushort16*)alloc((size_t)N * 128 * 2);
    ushort16* B4 = (ushort16*)alloc((size_t)N * 128 * 2);

    hipMemsetAsync(deg, 0, (size_t)N * 4, stream);
    hipMemsetAsync(cnt, 0, (size_t)N * 4, stream);

    const int eb4 = (E / 4 + 255) / 256;   // blocks per quarter
    const int nb = (N + 255) / 256;
    const int pb = ((N + 1) / 2 + 3) / 4;  // 2 nodes/wave, 4 waves/block
    const int gb = (N + 127) / 128;        // 128 rows/block MFMA tiles
    const int nblk = (N + 1023) / 1024;    // 49 for N=50000 (<= 64 required)
    const int cb = (N * 64 + 1023) / 1024;

    // 4 quarter dispatches: profiler visibility below the 66us atomic wall
    for (int q = 0; q < 4; ++q) {
        int e0 = (int)((size_t)E * q / 4);
        int e1 = (int)((size_t)E * (q + 1) / 4);
        k_deg_cnt<<<eb4, 256, 0, stream>>>(src, dst, ew, deg, cnt, pos, e0, e1);
    }
    k_scan_blk<<<nblk, 256, 0, stream>>>(cnt, row_ptr, blk_sums, N);
    k_scan_top<<<1, 64, 0, stream>>>(blk_sums, row_ptr, nblk, N);
    k_fix_dis<<<nb, 256, 0, stream>>>(row_ptr, blk_sums, deg, dis, N);
    k_scatter<<<(E + 255) / 256, 256, 0, stream>>>(src, dst, ew, dis, row_ptr, pos, csr, E);
    k_concat_bf16<<<cb, 256, 0, stream>>>(x, pe, (uint32*)B0, N);
    k_pack_all<<<(16384 + 2048 + 255) / 256, 256, 0, stream>>>(W1, W2, Wmu, Wlv, W1p, W2p, WHp);

    // layer 1: Y1=P*B0, Y2=P*Y1, Y3=P*Y2 -> gemm(transformed W1) -> relu -> B4
    k_prop<<<pb, 256, 0, stream>>>((uint32*)B0, csr, row_ptr, (uint32*)B1, N);
    k_prop<<<pb, 256, 0, stream>>>((uint32*)B1, csr, row_ptr, (uint32*)B2, N);
    k_prop<<<pb, 256, 0, stream>>>((uint32*)B2, csr, row_ptr, (uint32*)B3, N);
    k_mfma_gemm512<true><<<gb, 256, 0, stream>>>(B0, B1, B2, B3, W1p, b1, B4, N);

    // layer 2: Y1=P*B4, Y2, Y3 -> gemm(transformed W2) -> relu -> B3
    k_prop<<<pb, 256, 0, stream>>>((uint32*)B4, csr, row_ptr, (uint32*)B0, N);
    k_prop<<<pb, 256, 0, stream>>>((uint32*)B0, csr, row_ptr, (uint32*)B1, N);
    k_prop<<<pb, 256, 0, stream>>>((uint32*)B1, csr, row_ptr, (uint32*)B2, N);
    k_mfma_gemm512<true><<<gb, 256, 0, stream>>>(B4, B0, B1, B2, W2p, b2, B3, N);

    // heads -> d_out = [mu ; logvar] fp32
    k_mfma_head<<<gb, 256, 0, stream>>>(B3, WHp, bmu, blv, (float*)d_out, N);
}